// Round 1
// baseline (11092.815 us; speedup 1.0000x reference)
//
#include <hip/hip_runtime.h>
#include <hip/hip_bf16.h>
#include <stdint.h>

// Problem dims
#define T_  48
#define B_  16
#define H_  16
#define W_  48
#define HW_ 768
#define D_  684
#define N_  256
#define M_  256
#define A_  512
#define K2_ 121

// Workspace layout (float offsets). Total ~5.45M floats (~21.8 MB).
#define OFF_SZ     0u         // T*B*N embedding proj z (incl bias)
#define OFF_SR     196608u
#define OFF_SH     393216u
#define OFF_UHZT   589824u    // 9 square 256x256 transposes, contiguous:
#define OFF_UHRT   655360u
#define OFF_UHHT   720896u
#define OFF_UHZ2T  786432u
#define OFF_UHR2T  851968u
#define OFF_UHH2T  917504u
#define OFF_WYZT   983040u
#define OFF_WYRT   1048576u
#define OFF_WYHT   1114112u
#define OFF_WAT    1179648u   // [k=256][a=512]
#define OFF_WCZT   1310720u   // [d=684][n=256]
#define OFF_WCRT   1485824u
#define OFF_WCHT   1660928u
#define OFF_UAT    1836032u   // [d=684][a=512]
#define OFF_KC     2186240u   // K_comb^T [k=121][a=512]
#define OFF_H      2248192u   // h state  B*N
#define OFF_H1     2252288u   // h1 state B*N
#define OFF_WAH    2256384u   // Wa*h1 + Ua_b + Uf_b  B*A
#define OFF_DEN    2264576u   // 16 softmax denominators
#define OFF_CT     2264592u   // ct state B*D
#define OFF_AP     2275536u   // alpha_past B*HW
#define OFF_AUN    2287824u   // unnormalized alpha B*HW
#define OFF_UACTX  2300112u   // Ua_ctx bf16 [b][hw][a] : B*HW*A ushorts (=3145728 floats)

// d_out offsets
#define OUT_H2 0u
#define OUT_CT 196608u
#define OUT_AL 721920u
#define OUT_AP 1311744u

__device__ __forceinline__ float sigf(float x)  { return 1.f / (1.f + __expf(-x)); }
__device__ __forceinline__ float tanhf_(float x){ float e = __expf(2.f*x); return 1.f - 2.f/(e + 1.f); }
__device__ __forceinline__ float bf_lo(unsigned int u){ return __uint_as_float(u << 16); }
__device__ __forceinline__ float bf_hi(unsigned int u){ return __uint_as_float(u & 0xffff0000u); }
__device__ __forceinline__ unsigned short f2bf(float f){
  unsigned int x = __float_as_uint(f);
  return (unsigned short)((x + 0x7fffu + ((x >> 16) & 1u)) >> 16);  // RNE
}

// ---------------- prep: weight transposes + zero alpha_past ----------------
__global__ void k_prep(const float* __restrict__ Uhz, const float* __restrict__ Uhr, const float* __restrict__ Uhh,
                       const float* __restrict__ Uhz2, const float* __restrict__ Uhr2, const float* __restrict__ Uhh2,
                       const float* __restrict__ Wyz, const float* __restrict__ Wyr, const float* __restrict__ Wyh,
                       const float* __restrict__ Wa, const float* __restrict__ Wcz, const float* __restrict__ Wcr,
                       const float* __restrict__ Wch, const float* __restrict__ Ua, float* __restrict__ ws)
{
  int i = blockIdx.x * 256 + threadIdx.x;
  if (i < 589824) {                     // 9 x (256x256) -> [k][n]
    int m = i >> 16, rem = i & 65535, r = rem >> 8, c = rem & 255;
    const float* s;
    switch (m) { case 0: s=Uhz; break; case 1: s=Uhr; break; case 2: s=Uhh; break;
                 case 3: s=Uhz2; break; case 4: s=Uhr2; break; case 5: s=Uhh2; break;
                 case 6: s=Wyz; break; case 7: s=Wyr; break; default: s=Wyh; }
    ws[OFF_UHZT + m*65536 + c*256 + r] = s[rem];
  } else if (i < 720896) {              // Wa [512][256] -> WaT [256][512]
    int j = i - 589824, r = j >> 8, c = j & 255;
    ws[OFF_WAT + c*512 + r] = Wa[j];
  } else if (i < 1246208) {             // Wc* [256][684] -> [684][256]
    int j = i - 720896; int m = j / 175104; int rem = j - m*175104;
    int r = rem / 684, c = rem - r*684;
    const float* s = (m == 0) ? Wcz : (m == 1) ? Wcr : Wch;
    ws[OFF_WCZT + m*175104 + c*256 + r] = s[rem];
  } else if (i < 1596416) {             // Ua [512][684] -> UaT [684][512]
    int j = i - 1246208; int r = j / 684, c = j - r*684;
    ws[OFF_UAT + c*512 + r] = Ua[j];
  } else if (i < 1608704) {             // zero alpha_past
    ws[OFF_AP + (i - 1596416)] = 0.f;
  }
}

// ---------------- K_comb[a][k] = sum_c Uf[a][c] * Qw[c][k], stored [k][a] ----------------
__global__ void k_kcomb(const float* __restrict__ Uf, const float* __restrict__ Qw, float* __restrict__ ws)
{
  __shared__ float s_uf[16 * 516];      // padded stride 516 to break bank conflicts
  int tid = threadIdx.x, a0 = blockIdx.x * 16;
  for (int i = tid; i < 16 * 512; i += 256) { int al = i >> 9, c = i & 511; s_uf[al*516 + c] = Uf[(a0 + al)*512 + c]; }
  __syncthreads();
  int al = tid & 15, kb = tid >> 4;
  for (int kk = kb; kk < 121; kk += 16) {
    float acc = 0.f;
    #pragma unroll 8
    for (int c = 0; c < 512; ++c) acc += s_uf[al*516 + c] * Qw[c*121 + kk];
    ws[OFF_KC + kk*512 + a0 + al] = acc;
  }
}

// ---------------- embedding projections for all (t,b) rows ----------------
__global__ void k_embproj(const float* __restrict__ emb, const float* __restrict__ bz,
                          const float* __restrict__ br, const float* __restrict__ bh,
                          float* __restrict__ ws)
{
  __shared__ __align__(16) float s_e[256 * 16];  // [m][r]
  int tid = threadIdx.x, row0 = blockIdx.x * 16;
  for (int i = tid; i < 4096; i += 256) { int r = i >> 8, m = i & 255; s_e[m*16 + r] = emb[(row0 + r)*256 + m]; }
  __syncthreads();
  int n = tid;
  float az[16], arr[16], ahh[16];
  float vz = bz[n], vr = br[n], vh = bh[n];
  #pragma unroll
  for (int r = 0; r < 16; ++r) { az[r] = vz; arr[r] = vr; ahh[r] = vh; }
  for (int m = 0; m < 256; ++m) {
    float wz = ws[OFF_WYZT + m*256 + n], wr = ws[OFF_WYRT + m*256 + n], wh = ws[OFF_WYHT + m*256 + n];
    #pragma unroll
    for (int r = 0; r < 16; ++r) { float e = s_e[m*16 + r]; az[r] += wz*e; arr[r] += wr*e; ahh[r] += wh*e; }
  }
  #pragma unroll
  for (int r = 0; r < 16; ++r) {
    int ro = (row0 + r)*256 + n;
    ws[OFF_SZ + ro] = az[r]; ws[OFF_SR + ro] = arr[r]; ws[OFF_SH + ro] = ahh[r];
  }
}

// ---------------- Ua_ctx[b][hw][a] = sum_d ctx[b][d][hw] * Ua[a][d], bf16 ----------------
__global__ void __launch_bounds__(512) k_uactx(const float* __restrict__ ctx, float* __restrict__ ws)
{
  __shared__ __align__(16) float s_c[684 * 16];  // [d][r]
  int tid = threadIdx.x;
  int b = blockIdx.x / 48, chunk = blockIdx.x % 48, hw0 = chunk * 16;
  for (int i = tid; i < 684*16; i += 512) {
    int d = i >> 4, r = i & 15;
    s_c[i] = ctx[((size_t)(b*684 + d))*768 + hw0 + r];
  }
  __syncthreads();
  int a = tid;
  float acc[16];
  #pragma unroll
  for (int r = 0; r < 16; ++r) acc[r] = 0.f;
  const float* uat = ws + OFF_UAT;
  for (int d = 0; d < 684; ++d) {
    float wv = uat[d*512 + a];
    const float4* cp = (const float4*)(s_c + d*16);
    float4 c0 = cp[0], c1 = cp[1], c2 = cp[2], c3 = cp[3];
    acc[0]  += wv*c0.x; acc[1]  += wv*c0.y; acc[2]  += wv*c0.z; acc[3]  += wv*c0.w;
    acc[4]  += wv*c1.x; acc[5]  += wv*c1.y; acc[6]  += wv*c1.z; acc[7]  += wv*c1.w;
    acc[8]  += wv*c2.x; acc[9]  += wv*c2.y; acc[10] += wv*c2.z; acc[11] += wv*c2.w;
    acc[12] += wv*c3.x; acc[13] += wv*c3.y; acc[14] += wv*c3.z; acc[15] += wv*c3.w;
  }
  unsigned short* up = (unsigned short*)(ws + OFF_UACTX);
  #pragma unroll
  for (int r = 0; r < 16; ++r) up[((size_t)(b*768 + hw0 + r))*512 + a] = f2bf(acc[r]);
}

// ---------------- GRU1: h1 from h (n-chunk blocks, all b) ----------------
__global__ void k_gru1(int t, const float* __restrict__ hprev, const float* __restrict__ maskp, float* __restrict__ ws)
{
  __shared__ float s_h[4096];
  int tid = threadIdx.x;
  for (int i = tid; i < 4096; i += 256) s_h[i] = hprev[i];
  __syncthreads();
  int bl = tid >> 4, nl = tid & 15, n = blockIdx.x * 16 + nl;
  int ro = (t*16 + bl)*256 + n;
  float z = ws[OFF_SZ + ro], r = ws[OFF_SR + ro], sh = ws[OFF_SH + ro], uh = 0.f;
  const float* hb = s_h + bl*256;
  #pragma unroll 4
  for (int k = 0; k < 256; ++k) {
    float hv = hb[k];
    z  += ws[OFF_UHZT + k*256 + n] * hv;
    r  += ws[OFF_UHRT + k*256 + n] * hv;
    uh += ws[OFF_UHHT + k*256 + n] * hv;
  }
  float z1 = sigf(z), r1 = sigf(r);
  float h1p = tanhf_(uh * r1 + sh);
  float hvn = hb[n];
  float h1v = z1*hvn + (1.f - z1)*h1p;
  float m = maskp[t*16 + bl];
  h1v = m*h1v + (1.f - m)*hvn;
  ws[OFF_H1 + bl*256 + n] = h1v;
  if (blockIdx.x == 0 && tid < 16) ws[OFF_DEN + tid] = 0.f;  // denom for this step
}

// ---------------- WaH[b][a] = Wa*h1 + Ua_b + Uf_b ----------------
__global__ void k_wah(const float* __restrict__ Uab, const float* __restrict__ Ufb, float* __restrict__ ws)
{
  __shared__ float s_h1[256];
  int tid = threadIdx.x;
  int b = blockIdx.x >> 1, a0 = (blockIdx.x & 1) * 256;
  s_h1[tid] = ws[OFF_H1 + b*256 + tid];
  __syncthreads();
  int a = a0 + tid;
  float acc = Uab[a] + Ufb[a];
  #pragma unroll 4
  for (int k = 0; k < 256; ++k) acc += ws[OFF_WAT + k*512 + a] * s_h1[k];
  ws[OFF_WAH + b*512 + a] = acc;
}

// ---------------- fused coverage conv + tanh + va-reduce + exp + denom ----------------
__global__ void k_cover_e(const float* __restrict__ cmask, const float* __restrict__ va,
                          const float* __restrict__ vab, float* __restrict__ ws)
{
  __shared__ __align__(16) float s_ap[26 * 58];   // padded alpha_past
  __shared__ __align__(16) float s_kc[121 * 68];  // K_comb tile [k][64], stride 68
  __shared__ __align__(16) float s_wah[512];
  __shared__ __align__(16) float s_va[512];
  __shared__ float s_red[4];
  int tid = threadIdx.x;
  int b = blockIdx.x / 12, row0 = (blockIdx.x % 12) * 64;
  for (int i = tid; i < 512; i += 256) { s_wah[i] = ws[OFF_WAH + b*512 + i]; s_va[i] = va[i]; }
  for (int i = tid; i < 26*58; i += 256) {
    int ph = i / 58, pw = i - ph*58;
    int hh = ph - 5, wp = pw - 5;
    float v = 0.f;
    if (hh >= 0 && hh < 16 && wp >= 0 && wp < 48) v = ws[OFF_AP + b*768 + hh*48 + wp];
    s_ap[i] = v;
  }
  int agrp = tid & 3, rowl = tid >> 2;
  int hw = row0 + rowl, hq = hw / 48, wq = hw - hq*48;
  int pbase = hq*58 + wq, acol = agrp*16;
  const unsigned short* uact = (const unsigned short*)(ws + OFF_UACTX);
  float e_acc = 0.f;
  for (int tile = 0; tile < 8; ++tile) {
    int atile = tile * 64;
    __syncthreads();
    for (int i = tid; i < 121*64; i += 256) { int k = i >> 6, c = i & 63; s_kc[k*68 + c] = ws[OFF_KC + k*512 + atile + c]; }
    __syncthreads();
    const uint4* up = (const uint4*)(uact + ((size_t)(b*768 + hw))*512 + atile + acol);
    uint4 u0 = up[0], u1 = up[1];
    const float4* wp = (const float4*)(s_wah + atile + acol);
    float4 w0 = wp[0], w1 = wp[1], w2 = wp[2], w3 = wp[3];
    float4 a0, a1, a2, a3;
    a0.x = bf_lo(u0.x) + w0.x; a0.y = bf_hi(u0.x) + w0.y; a0.z = bf_lo(u0.y) + w0.z; a0.w = bf_hi(u0.y) + w0.w;
    a1.x = bf_lo(u0.z) + w1.x; a1.y = bf_hi(u0.z) + w1.y; a1.z = bf_lo(u0.w) + w1.z; a1.w = bf_hi(u0.w) + w1.w;
    a2.x = bf_lo(u1.x) + w2.x; a2.y = bf_hi(u1.x) + w2.y; a2.z = bf_lo(u1.y) + w2.z; a2.w = bf_hi(u1.y) + w2.w;
    a3.x = bf_lo(u1.z) + w3.x; a3.y = bf_hi(u1.z) + w3.y; a3.z = bf_lo(u1.w) + w3.z; a3.w = bf_hi(u1.w) + w3.w;
    for (int kh = 0; kh < 11; ++kh) {
      int pb = pbase + kh*58, kb = kh*11;
      #pragma unroll
      for (int kw = 0; kw < 11; ++kw) {
        float p = s_ap[pb + kw];
        const float4* kc = (const float4*)(s_kc + (kb + kw)*68 + acol);
        float4 k0 = kc[0], k1 = kc[1], k2 = kc[2], k3 = kc[3];
        a0.x += p*k0.x; a0.y += p*k0.y; a0.z += p*k0.z; a0.w += p*k0.w;
        a1.x += p*k1.x; a1.y += p*k1.y; a1.z += p*k1.z; a1.w += p*k1.w;
        a2.x += p*k2.x; a2.y += p*k2.y; a2.z += p*k2.z; a2.w += p*k2.w;
        a3.x += p*k3.x; a3.y += p*k3.y; a3.z += p*k3.z; a3.w += p*k3.w;
      }
    }
    const float4* vp = (const float4*)(s_va + atile + acol);
    float4 v0 = vp[0], v1 = vp[1], v2 = vp[2], v3 = vp[3];
    e_acc += v0.x*tanhf_(a0.x) + v0.y*tanhf_(a0.y) + v0.z*tanhf_(a0.z) + v0.w*tanhf_(a0.w);
    e_acc += v1.x*tanhf_(a1.x) + v1.y*tanhf_(a1.y) + v1.z*tanhf_(a1.z) + v1.w*tanhf_(a1.w);
    e_acc += v2.x*tanhf_(a2.x) + v2.y*tanhf_(a2.y) + v2.z*tanhf_(a2.z) + v2.w*tanhf_(a2.w);
    e_acc += v3.x*tanhf_(a3.x) + v3.y*tanhf_(a3.y) + v3.z*tanhf_(a3.z) + v3.w*tanhf_(a3.w);
  }
  e_acc += __shfl_xor(e_acc, 1);
  e_acc += __shfl_xor(e_acc, 2);
  float e  = e_acc + vab[0];
  float un = __expf(e) * cmask[b*768 + hw];
  if (agrp == 0) ws[OFF_AUN + b*768 + hw] = un;
  float v = (agrp == 0) ? un : 0.f;
  v += __shfl_xor(v, 4); v += __shfl_xor(v, 8); v += __shfl_xor(v, 16); v += __shfl_xor(v, 32);
  if ((tid & 63) == 0) s_red[tid >> 6] = v;
  __syncthreads();
  if (tid == 0) atomicAdd(&ws[OFF_DEN + b], s_red[0] + s_red[1] + s_red[2] + s_red[3]);
}

// ---------------- normalize alpha, update alpha_past, ct = ctx . alpha ----------------
__global__ void k_alpha_ct(int t, const float* __restrict__ ctx, float* __restrict__ out, float* __restrict__ ws)
{
  __shared__ __align__(16) float s_al[768];
  __shared__ float s_inv;
  int tid = threadIdx.x;
  int b = blockIdx.x / 11, dc = blockIdx.x % 11;
  if (tid == 0) s_inv = 1.f / ws[OFF_DEN + b];
  __syncthreads();
  float inv = s_inv;
  for (int i = tid; i < 768; i += 256) s_al[i] = ws[OFF_AUN + b*768 + i] * inv;
  __syncthreads();
  if (dc == 0) {
    float* outA = out + OUT_AL + (size_t)(t*16 + b)*768;
    float* outP = out + OUT_AP + (size_t)(t*16 + b)*768;
    for (int i = tid; i < 768; i += 256) {
      float av = s_al[i];
      float np = ws[OFF_AP + b*768 + i] + av;
      ws[OFF_AP + b*768 + i] = np;
      outA[i] = av; outP[i] = np;
    }
  }
  int d = dc*64 + (tid >> 2), q = tid & 3;
  if (d < 684) {
    const float4* cp = (const float4*)(ctx + ((size_t)(b*684 + d))*768 + q*192);
    const float4* ap_ = (const float4*)(s_al + q*192);
    float s = 0.f;
    #pragma unroll 8
    for (int i = 0; i < 48; ++i) {
      float4 cv = cp[i]; float4 av = ap_[i];
      s += cv.x*av.x + cv.y*av.y + cv.z*av.z + cv.w*av.w;
    }
    s += __shfl_xor(s, 1); s += __shfl_xor(s, 2);
    if (q == 0) {
      ws[OFF_CT + b*684 + d] = s;
      out[OUT_CT + (size_t)(t*16 + b)*684 + d] = s;
    }
  }
}

// ---------------- GRU2: h2 from ct, h1 ----------------
__global__ void k_gru2(int t, const float* __restrict__ maskp,
                       const float* __restrict__ bz2, const float* __restrict__ br2, const float* __restrict__ bh2,
                       float* __restrict__ out, float* __restrict__ ws)
{
  __shared__ float s_ct[16 * 684];
  __shared__ float s_h1[4096];
  int tid = threadIdx.x;
  for (int i = tid; i < 16*684; i += 256) s_ct[i] = ws[OFF_CT + i];
  for (int i = tid; i < 4096; i += 256) s_h1[i] = ws[OFF_H1 + i];
  __syncthreads();
  int bl = tid >> 4, nl = tid & 15, n = blockIdx.x * 16 + nl;
  float z = bz2[n], r = br2[n], uh = bh2[n], ch = 0.f;
  const float* cb = s_ct + bl*684;
  #pragma unroll 4
  for (int d = 0; d < 684; ++d) {
    float c = cb[d];
    z  += ws[OFF_WCZT + d*256 + n] * c;
    r  += ws[OFF_WCRT + d*256 + n] * c;
    ch += ws[OFF_WCHT + d*256 + n] * c;
  }
  const float* hb = s_h1 + bl*256;
  #pragma unroll 4
  for (int k = 0; k < 256; ++k) {
    float hv = hb[k];
    z  += ws[OFF_UHZ2T + k*256 + n] * hv;
    r  += ws[OFF_UHR2T + k*256 + n] * hv;
    uh += ws[OFF_UHH2T + k*256 + n] * hv;
  }
  float z2 = sigf(z), r2 = sigf(r);
  float h2p = tanhf_(ch + uh * r2);
  float h1vn = hb[n];
  float h2 = z2*h1vn + (1.f - z2)*h2p;
  float m = maskp[t*16 + bl];
  h2 = m*h2 + (1.f - m)*h1vn;
  out[OUT_H2 + (size_t)(t*16 + bl)*256 + n] = h2;
  ws[OFF_H + bl*256 + n] = h2;
}

extern "C" void kernel_launch(void* const* d_in, const int* in_sizes, int n_in,
                              void* d_out, int out_size, void* d_ws, size_t ws_size,
                              hipStream_t stream)
{
  const float* emb   = (const float*)d_in[0];
  const float* maskp = (const float*)d_in[1];
  const float* ctx   = (const float*)d_in[2];
  const float* cmask = (const float*)d_in[3];
  const float* inits = (const float*)d_in[4];
  const float* Ua    = (const float*)d_in[5];
  const float* Uab   = (const float*)d_in[6];
  const float* Wa    = (const float*)d_in[7];
  const float* Qw    = (const float*)d_in[8];
  const float* Uf    = (const float*)d_in[9];
  const float* Ufb   = (const float*)d_in[10];
  const float* va    = (const float*)d_in[11];
  const float* vab   = (const float*)d_in[12];
  const float* Wyz   = (const float*)d_in[13];
  const float* Wyzb  = (const float*)d_in[14];
  const float* Wyr   = (const float*)d_in[15];
  const float* Wyrb  = (const float*)d_in[16];
  const float* Wyh   = (const float*)d_in[17];
  const float* Wyhb  = (const float*)d_in[18];
  const float* Uhz   = (const float*)d_in[19];
  const float* Uhr   = (const float*)d_in[20];
  const float* Uhh   = (const float*)d_in[21];
  const float* Wcz   = (const float*)d_in[22];
  const float* Wcr   = (const float*)d_in[23];
  const float* Wch   = (const float*)d_in[24];
  const float* Uhz2  = (const float*)d_in[25];
  const float* Uhz2b = (const float*)d_in[26];
  const float* Uhr2  = (const float*)d_in[27];
  const float* Uhr2b = (const float*)d_in[28];
  const float* Uhh2  = (const float*)d_in[29];
  const float* Uhh2b = (const float*)d_in[30];
  float* out = (float*)d_out;
  float* ws  = (float*)d_ws;

  k_prep<<<dim3(6284), dim3(256), 0, stream>>>(Uhz, Uhr, Uhh, Uhz2, Uhr2, Uhh2,
                                               Wyz, Wyr, Wyh, Wa, Wcz, Wcr, Wch, Ua, ws);
  k_kcomb<<<dim3(32), dim3(256), 0, stream>>>(Uf, Qw, ws);
  k_embproj<<<dim3(48), dim3(256), 0, stream>>>(emb, Wyzb, Wyrb, Wyhb, ws);
  k_uactx<<<dim3(768), dim3(512), 0, stream>>>(ctx, ws);

  for (int t = 0; t < 48; ++t) {
    const float* hprev = (t == 0) ? inits : (ws + OFF_H);
    k_gru1<<<dim3(16), dim3(256), 0, stream>>>(t, hprev, maskp, ws);
    k_wah<<<dim3(32), dim3(256), 0, stream>>>(Uab, Ufb, ws);
    k_cover_e<<<dim3(192), dim3(256), 0, stream>>>(cmask, va, vab, ws);
    k_alpha_ct<<<dim3(176), dim3(256), 0, stream>>>(t, ctx, out, ws);
    k_gru2<<<dim3(16), dim3(256), 0, stream>>>(t, maskp, Uhz2b, Uhr2b, Uhh2b, out, ws);
  }
  (void)in_sizes; (void)n_in; (void)out_size; (void)ws_size;
}

// Round 3
// 3983.606 us; speedup vs baseline: 2.7846x; 2.7846x over previous
//
#include <hip/hip_runtime.h>
#include <hip/hip_bf16.h>
#include <stdint.h>

// Problem dims
#define T_  48
#define B_  16
#define H_  16
#define W_  48
#define HW_ 768
#define D_  684
#define N_  256
#define M_  256
#define A_  512

// Workspace layout (float offsets).  R2 BUG FIX: KCB is 512*128 ushorts =
// 32768 floats (was under-allocated at 16384 -> G1/G2 clobbered it -> NaN).
#define OFF_SZ     0u
#define OFF_SR     196608u
#define OFF_SH     393216u
#define OFF_UHZT   589824u    // 9 square 256x256 transposes [k][n]
#define OFF_UHRT   655360u
#define OFF_UHHT   720896u
#define OFF_UHZ2T  786432u
#define OFF_UHR2T  851968u
#define OFF_UHH2T  917504u
#define OFF_WYZT   983040u
#define OFF_WYRT   1048576u
#define OFF_WYHT   1114112u
#define OFF_WAT    1179648u   // [k=256][a=512]
#define OFF_WCZT   1310720u   // [d=684][n=256] x3
#define OFF_UAT    1836032u   // [d=684][a=512]
#define OFF_KCB    2186240u   // K_comb^T bf16 [a=512][k=128] = 65536 ushorts = 32768 floats
#define OFF_G1     2219008u   // gates1 [b][3][256] = 12288
#define OFF_G2     2231296u   // gates2 [b][4][256] = 16384
#define OFF_H      2247680u   // h state  B*N = 4096
#define OFF_H1     2251776u   // h1 state B*N = 4096
#define OFF_WAH    2255872u   // Wa*h1 + Ua_b + Uf_b  B*A = 8192
#define OFF_CT     2264064u   // ct state B*D = 10944
#define OFF_AP     2275008u   // alpha_past B*HW = 12288
#define OFF_AUN    2287296u   // per-step e partial sums (atomic) B*HW = 12288
#define OFF_UACTX  2299584u   // Ua_ctx bf16 [b][hw][a] = 3145728 floats; end 5445312

// d_out offsets
#define OUT_H2 0u
#define OUT_CT 196608u
#define OUT_AL 721920u
#define OUT_AP 1311744u

typedef __attribute__((ext_vector_type(8))) short bf16x8;
typedef __attribute__((ext_vector_type(16))) float floatx16;

__device__ __forceinline__ float sigf(float x)  { return 1.f / (1.f + __expf(-x)); }
__device__ __forceinline__ float tanhf_(float x){ float e = __expf(2.f*x); return 1.f - 2.f/(e + 1.f); }
__device__ __forceinline__ float bfval(unsigned short u){ return __uint_as_float(((unsigned)u) << 16); }
__device__ __forceinline__ unsigned short f2bf(float f){
  unsigned int x = __float_as_uint(f);
  return (unsigned short)((x + 0x7fffu + ((x >> 16) & 1u)) >> 16);  // RNE
}

// ---------------- prep: weight transposes + zero alpha_past ----------------
__global__ void k_prep(const float* __restrict__ Uhz, const float* __restrict__ Uhr, const float* __restrict__ Uhh,
                       const float* __restrict__ Uhz2, const float* __restrict__ Uhr2, const float* __restrict__ Uhh2,
                       const float* __restrict__ Wyz, const float* __restrict__ Wyr, const float* __restrict__ Wyh,
                       const float* __restrict__ Wa, const float* __restrict__ Wcz, const float* __restrict__ Wcr,
                       const float* __restrict__ Wch, const float* __restrict__ Ua, float* __restrict__ ws)
{
  int i = blockIdx.x * 256 + threadIdx.x;
  if (i < 589824) {                     // 9 x (256x256) -> [k][n]
    int m = i >> 16, rem = i & 65535, r = rem >> 8, c = rem & 255;
    const float* s;
    switch (m) { case 0: s=Uhz; break; case 1: s=Uhr; break; case 2: s=Uhh; break;
                 case 3: s=Uhz2; break; case 4: s=Uhr2; break; case 5: s=Uhh2; break;
                 case 6: s=Wyz; break; case 7: s=Wyr; break; default: s=Wyh; }
    ws[OFF_UHZT + m*65536 + c*256 + r] = s[rem];
  } else if (i < 720896) {              // Wa [512][256] -> WaT [256][512]
    int j = i - 589824, r = j >> 8, c = j & 255;
    ws[OFF_WAT + c*512 + r] = Wa[j];
  } else if (i < 1246208) {             // Wc* [256][684] -> [684][256]
    int j = i - 720896; int m = j / 175104; int rem = j - m*175104;
    int r = rem / 684, c = rem - r*684;
    const float* s = (m == 0) ? Wcz : (m == 1) ? Wcr : Wch;
    ws[OFF_WCZT + m*175104 + c*256 + r] = s[rem];
  } else if (i < 1596416) {             // Ua [512][684] -> UaT [684][512]
    int j = i - 1246208; int r = j / 684, c = j - r*684;
    ws[OFF_UAT + c*512 + r] = Ua[j];
  } else if (i < 1608704) {             // zero alpha_past
    ws[OFF_AP + (i - 1596416)] = 0.f;
  }
}

// ---------------- K_comb^T bf16 [a=512][k=128]: KC[a][k] = sum_c Uf[a][c]*Qw[c][k] ----------------
__global__ void k_kcomb(const float* __restrict__ Uf, const float* __restrict__ Qw, float* __restrict__ ws)
{
  __shared__ float s_uf[16 * 516];
  int tid = threadIdx.x, a0 = blockIdx.x * 16;
  for (int i = tid; i < 16 * 512; i += 256) { int al = i >> 9, c = i & 511; s_uf[al*516 + c] = Uf[(a0 + al)*512 + c]; }
  __syncthreads();
  int al = tid & 15, kb = tid >> 4;
  unsigned short* kcb = (unsigned short*)(ws + OFF_KCB);
  for (int kk = kb; kk < 128; kk += 16) {
    float acc = 0.f;
    if (kk < 121) {
      #pragma unroll 8
      for (int c = 0; c < 512; ++c) acc += s_uf[al*516 + c] * Qw[c*121 + kk];
    }
    kcb[(size_t)(a0 + al)*128 + kk] = f2bf(acc);
  }
}

// ---------------- embedding projections for all (t,b) rows ----------------
__global__ void k_embproj(const float* __restrict__ emb, const float* __restrict__ bz,
                          const float* __restrict__ br, const float* __restrict__ bh,
                          float* __restrict__ ws)
{
  __shared__ __align__(16) float s_e[256 * 16];
  int tid = threadIdx.x, row0 = blockIdx.x * 16;
  for (int i = tid; i < 4096; i += 256) { int r = i >> 8, m = i & 255; s_e[m*16 + r] = emb[(row0 + r)*256 + m]; }
  __syncthreads();
  int n = tid;
  float az[16], arr[16], ahh[16];
  float vz = bz[n], vr = br[n], vh = bh[n];
  #pragma unroll
  for (int r = 0; r < 16; ++r) { az[r] = vz; arr[r] = vr; ahh[r] = vh; }
  for (int m = 0; m < 256; ++m) {
    float wz = ws[OFF_WYZT + m*256 + n], wr = ws[OFF_WYRT + m*256 + n], wh = ws[OFF_WYHT + m*256 + n];
    #pragma unroll
    for (int r = 0; r < 16; ++r) { float e = s_e[m*16 + r]; az[r] += wz*e; arr[r] += wr*e; ahh[r] += wh*e; }
  }
  #pragma unroll
  for (int r = 0; r < 16; ++r) {
    int ro = (row0 + r)*256 + n;
    ws[OFF_SZ + ro] = az[r]; ws[OFF_SR + ro] = arr[r]; ws[OFF_SH + ro] = ahh[r];
  }
}

// ---------------- Ua_ctx[b][hw][a] bf16 ----------------
__global__ void __launch_bounds__(512) k_uactx(const float* __restrict__ ctx, float* __restrict__ ws)
{
  __shared__ __align__(16) float s_c[684 * 16];
  int tid = threadIdx.x;
  int b = blockIdx.x / 48, chunk = blockIdx.x % 48, hw0 = chunk * 16;
  for (int i = tid; i < 684*16; i += 512) {
    int d = i >> 4, r = i & 15;
    s_c[i] = ctx[((size_t)(b*684 + d))*768 + hw0 + r];
  }
  __syncthreads();
  int a = tid;
  float acc[16];
  #pragma unroll
  for (int r = 0; r < 16; ++r) acc[r] = 0.f;
  const float* uat = ws + OFF_UAT;
  for (int d = 0; d < 684; ++d) {
    float wv = uat[d*512 + a];
    const float4* cp = (const float4*)(s_c + d*16);
    float4 c0 = cp[0], c1 = cp[1], c2 = cp[2], c3 = cp[3];
    acc[0]  += wv*c0.x; acc[1]  += wv*c0.y; acc[2]  += wv*c0.z; acc[3]  += wv*c0.w;
    acc[4]  += wv*c1.x; acc[5]  += wv*c1.y; acc[6]  += wv*c1.z; acc[7]  += wv*c1.w;
    acc[8]  += wv*c2.x; acc[9]  += wv*c2.y; acc[10] += wv*c2.z; acc[11] += wv*c2.w;
    acc[12] += wv*c3.x; acc[13] += wv*c3.y; acc[14] += wv*c3.z; acc[15] += wv*c3.w;
  }
  unsigned short* up = (unsigned short*)(ws + OFF_UACTX);
  #pragma unroll
  for (int r = 0; r < 16; ++r) up[((size_t)(b*768 + hw0 + r))*512 + a] = f2bf(acc[r]);
}

// ---------------- gates1: combine prev-step h2, then G1[b][g] = Uh{g}[k][n] . h ----------------
__global__ void __launch_bounds__(256) k_gates1(int t, const float* __restrict__ inits, const float* __restrict__ maskp,
                                                const float* __restrict__ bz2, const float* __restrict__ br2,
                                                const float* __restrict__ bh2,
                                                float* __restrict__ out, float* __restrict__ ws)
{
  __shared__ float s_h[256];
  __shared__ float s_p[4][256];
  int tid = threadIdx.x;
  int b = blockIdx.x / 3, g = blockIdx.x % 3;
  {
    int n = tid;
    float hv;
    if (t == 0) {
      hv = inits[b*256 + n];
    } else {
      float h1 = ws[OFF_H1 + b*256 + n];
      float z2 = sigf(ws[OFF_G2 + (b*4 + 0)*256 + n] + bz2[n]);
      float r2 = sigf(ws[OFF_G2 + (b*4 + 1)*256 + n] + br2[n]);
      float h2p = tanhf_(ws[OFF_G2 + (b*4 + 2)*256 + n] + (ws[OFF_G2 + (b*4 + 3)*256 + n] + bh2[n]) * r2);
      float h2 = z2*h1 + (1.f - z2)*h2p;
      float m = maskp[(t-1)*16 + b];
      hv = m*h2 + (1.f - m)*h1;
      if (g == 0) out[OUT_H2 + (size_t)((t-1)*16 + b)*256 + n] = hv;
    }
    s_h[n] = hv;
    if (g == 0) ws[OFF_H + b*256 + n] = hv;
  }
  if (g == 0) for (int i = tid; i < 768; i += 256) ws[OFF_AUN + b*768 + i] = 0.f;
  __syncthreads();
  int nq = tid & 63, kq = tid >> 6;
  const float* Wbase = ws + OFF_UHZT + g*65536;
  float4 acc = {0.f,0.f,0.f,0.f};
  #pragma unroll 4
  for (int k = kq*64; k < kq*64 + 64; ++k) {
    float hk = s_h[k];
    float4 wv = *(const float4*)(Wbase + k*256 + nq*4);
    acc.x += wv.x*hk; acc.y += wv.y*hk; acc.z += wv.z*hk; acc.w += wv.w*hk;
  }
  *(float4*)(&s_p[kq][nq*4]) = acc;
  __syncthreads();
  if (tid < 256) {
    float v = s_p[0][tid] + s_p[1][tid] + s_p[2][tid] + s_p[3][tid];
    ws[OFF_G1 + (b*3 + g)*256 + tid] = v;
  }
}

// ---------------- h1 elementwise + WaH = Wa.h1 + Ua_b + Uf_b ----------------
__global__ void __launch_bounds__(256) k_h1wah(int t, const float* __restrict__ maskp,
                                               const float* __restrict__ Uab, const float* __restrict__ Ufb,
                                               float* __restrict__ ws)
{
  __shared__ float s_h1[256];
  __shared__ float s_p[4][256];
  int tid = threadIdx.x;
  int b = blockIdx.x >> 1, ah = blockIdx.x & 1;
  {
    int n = tid; int ro = (t*16 + b)*256 + n;
    float h  = ws[OFF_H + b*256 + n];
    float z1 = sigf(ws[OFF_G1 + (b*3+0)*256 + n] + ws[OFF_SZ + ro]);
    float r1 = sigf(ws[OFF_G1 + (b*3+1)*256 + n] + ws[OFF_SR + ro]);
    float h1p = tanhf_(ws[OFF_G1 + (b*3+2)*256 + n] * r1 + ws[OFF_SH + ro]);
    float m = maskp[t*16 + b];
    float h1 = z1*h + (1.f - z1)*h1p;
    h1 = m*h1 + (1.f - m)*h;
    s_h1[n] = h1;
    if (ah == 0) ws[OFF_H1 + b*256 + n] = h1;
  }
  __syncthreads();
  int aq = tid & 63, kq = tid >> 6;
  int a0 = ah*256;
  float4 acc = {0.f,0.f,0.f,0.f};
  #pragma unroll 4
  for (int k = kq*64; k < kq*64 + 64; ++k) {
    float hk = s_h1[k];
    float4 wv = *(const float4*)(ws + OFF_WAT + k*512 + a0 + aq*4);
    acc.x += wv.x*hk; acc.y += wv.y*hk; acc.z += wv.z*hk; acc.w += wv.w*hk;
  }
  *(float4*)(&s_p[kq][aq*4]) = acc;
  __syncthreads();
  if (tid < 256) {
    int a = a0 + tid;
    float v = s_p[0][tid] + s_p[1][tid] + s_p[2][tid] + s_p[3][tid];
    ws[OFF_WAH + b*512 + a] = v + Uab[a] + Ufb[a];
  }
}

// ---------------- cover: bf16 MFMA GEMM (im2col x K_comb^T) + tanh + va partial e ----------------
// grid 384 = b(16) x mt(12) x nt2(2); block 256 = 4 waves (mw x nw)
__global__ void __launch_bounds__(256) k_cover(const float* __restrict__ va, float* __restrict__ ws)
{
  __shared__ unsigned short sA[64 * 136];
  __shared__ float sWah[512];
  __shared__ float sVa[512];
  int tid = threadIdx.x;
  int blk = blockIdx.x;
  int b = blk / 24; int rem = blk % 24; int mt = rem >> 1; int nt2 = rem & 1;
  for (int i = tid; i < 512; i += 256) { sWah[i] = ws[OFF_WAH + b*512 + i]; sVa[i] = va[i]; }
  const float* ap = ws + OFF_AP + b*768;
  for (int idx = tid; idx < 64*128; idx += 256) {
    int r = idx & 63, k = idx >> 6;
    int hw = mt*64 + r; int hh = hw / 48; int wwp = hw - hh*48;
    float v = 0.f;
    if (k < 121) {
      int kh = k / 11, kw = k - kh*11;
      int shh = hh + kh - 5, sww = wwp + kw - 5;
      if (shh >= 0 && shh < 16 && sww >= 0 && sww < 48) v = ap[shh*48 + sww];
    }
    sA[r*136 + k] = f2bf(v);
  }
  __syncthreads();
  int lane = tid & 63; int w = tid >> 6; int mw = w >> 1; int nw = w & 1;
  int c5 = lane & 31; int q = lane >> 5;
  bf16x8 af[8];
  {
    int m = mw*32 + c5;
    #pragma unroll
    for (int ks = 0; ks < 8; ++ks)
      af[ks] = *(const bf16x8*)(sA + m*136 + ks*16 + q*8);
  }
  const unsigned short* kct = (const unsigned short*)(ws + OFF_KCB);
  const unsigned short* uact = (const unsigned short*)(ws + OFF_UACTX);
  float e_part[16];
  #pragma unroll
  for (int r = 0; r < 16; ++r) e_part[r] = 0.f;

  for (int sp = 0; sp < 2; ++sp) {
    int n_base = nt2*256 + nw*128 + sp*64;
    floatx16 acc[2];
    #pragma unroll
    for (int r = 0; r < 16; ++r) { acc[0][r] = 0.f; acc[1][r] = 0.f; }
    const bf16x8* kb0 = (const bf16x8*)(kct + (size_t)(n_base + c5)*128 + q*8);
    const bf16x8* kb1 = (const bf16x8*)(kct + (size_t)(n_base + 32 + c5)*128 + q*8);
    #pragma unroll
    for (int ks = 0; ks < 8; ++ks) {
      bf16x8 b0 = kb0[ks*2];
      bf16x8 b1 = kb1[ks*2];
      acc[0] = __builtin_amdgcn_mfma_f32_32x32x16_bf16(af[ks], b0, acc[0], 0, 0, 0);
      acc[1] = __builtin_amdgcn_mfma_f32_32x32x16_bf16(af[ks], b1, acc[1], 0, 0, 0);
    }
    #pragma unroll
    for (int half = 0; half < 2; ++half) {
      int col = n_base + half*32 + c5;       // global a in 0..511
      float vav = sVa[col], wah = sWah[col];
      #pragma unroll
      for (int r = 0; r < 16; ++r) {
        int row32 = (r & 3) + 8*(r >> 2) + 4*q;
        int hw = mt*64 + mw*32 + row32;
        float x = acc[half][r] + wah + bfval(uact[((size_t)(b*768 + hw))*512 + col]);
        e_part[r] += vav * tanhf_(x);
      }
    }
  }
  #pragma unroll
  for (int r = 0; r < 16; ++r) {
    float v = e_part[r];
    v += __shfl_xor(v, 1); v += __shfl_xor(v, 2); v += __shfl_xor(v, 4);
    v += __shfl_xor(v, 8); v += __shfl_xor(v, 16);
    e_part[r] = v;
  }
  if (c5 == 0) {
    #pragma unroll
    for (int r = 0; r < 16; ++r) {
      int row32 = (r & 3) + 8*(r >> 2) + 4*q;
      int hw = mt*64 + mw*32 + row32;
      atomicAdd(&ws[OFF_AUN + b*768 + hw], e_part[r]);
    }
  }
}

// ---------------- alpha: exp+denorm+normalize, ap update, ct = ctx . alpha ----------------
__global__ void __launch_bounds__(256) k_alpha_ct(int t, const float* __restrict__ ctx, const float* __restrict__ cmask,
                                                  const float* __restrict__ vab,
                                                  float* __restrict__ out, float* __restrict__ ws)
{
  __shared__ __align__(16) float s_al[768];
  __shared__ float s_red[4];
  __shared__ float s_inv;
  int tid = threadIdx.x;
  int b = blockIdx.x / 11, dc = blockIdx.x % 11;
  float vb = vab[0];
  float local = 0.f;
  for (int i = tid; i < 768; i += 256) {
    float e = ws[OFF_AUN + b*768 + i] + vb;
    float un = __expf(e) * cmask[b*768 + i];
    s_al[i] = un; local += un;
  }
  local += __shfl_xor(local, 1); local += __shfl_xor(local, 2); local += __shfl_xor(local, 4);
  local += __shfl_xor(local, 8); local += __shfl_xor(local, 16); local += __shfl_xor(local, 32);
  if ((tid & 63) == 0) s_red[tid >> 6] = local;
  __syncthreads();
  if (tid == 0) s_inv = 1.f / (s_red[0] + s_red[1] + s_red[2] + s_red[3]);
  __syncthreads();
  float inv = s_inv;
  for (int i = tid; i < 768; i += 256) s_al[i] *= inv;
  __syncthreads();
  if (dc == 0) {
    float* outA = out + OUT_AL + (size_t)(t*16 + b)*768;
    float* outP = out + OUT_AP + (size_t)(t*16 + b)*768;
    for (int i = tid; i < 768; i += 256) {
      float av = s_al[i];
      float np = ws[OFF_AP + b*768 + i] + av;
      ws[OFF_AP + b*768 + i] = np;
      outA[i] = av; outP[i] = np;
    }
  }
  int d = dc*64 + (tid >> 2), qq = tid & 3;
  if (d < 684) {
    const float4* cp  = (const float4*)(ctx + ((size_t)(b*684 + d))*768 + qq*192);
    const float4* ap_ = (const float4*)(s_al + qq*192);
    float s = 0.f;
    #pragma unroll 8
    for (int i = 0; i < 48; ++i) {
      float4 cv = cp[i]; float4 av = ap_[i];
      s += cv.x*av.x + cv.y*av.y + cv.z*av.z + cv.w*av.w;
    }
    s += __shfl_xor(s, 1); s += __shfl_xor(s, 2);
    if (qq == 0) {
      ws[OFF_CT + b*684 + d] = s;
      out[OUT_CT + (size_t)(t*16 + b)*684 + d] = s;
    }
  }
}

// ---------------- gates2: 4 matvecs (z,r: [ct|h1]x940; h_ct: ctx684; h_u: h1x256) ----------------
// grid 256 = b(16) x g(4) x q4(4); block 256
__global__ void __launch_bounds__(256) k_gates2(float* __restrict__ ws)
{
  __shared__ float s_a[960];
  __shared__ float s_p[16][64];
  int tid = threadIdx.x;
  int blk = blockIdx.x;
  int b = blk >> 4; int r4 = blk & 15; int g = r4 >> 2; int q4 = r4 & 3;
  for (int i = tid; i < 684; i += 256) s_a[i] = ws[OFF_CT + b*684 + i];
  if (tid < 256) s_a[684 + tid] = ws[OFF_H1 + b*256 + tid];
  __syncthreads();
  int nq = tid & 15, kq = tid >> 4;
  int n = q4*64 + nq*4;
  float4 acc = {0.f,0.f,0.f,0.f};
  if (g < 2) {
    int cs = 59, k0 = kq*cs, k1 = min(940, k0 + cs);
    int ka = min(k1, 684);
    for (int k = k0; k < ka; ++k) {
      float av = s_a[k];
      float4 wv = *(const float4*)(ws + OFF_WCZT + g*175104 + k*256 + n);
      acc.x += wv.x*av; acc.y += wv.y*av; acc.z += wv.z*av; acc.w += wv.w*av;
    }
    for (int k = (k0 > 684 ? k0 : 684); k < k1; ++k) {
      float av = s_a[k];
      float4 wv = *(const float4*)(ws + OFF_UHZ2T + g*65536 + (k - 684)*256 + n);
      acc.x += wv.x*av; acc.y += wv.y*av; acc.z += wv.z*av; acc.w += wv.w*av;
    }
  } else if (g == 2) {
    int cs = 43, k0 = kq*cs, k1 = min(684, k0 + cs);
    for (int k = k0; k < k1; ++k) {
      float av = s_a[k];
      float4 wv = *(const float4*)(ws + OFF_WCZT + 2*175104 + k*256 + n);
      acc.x += wv.x*av; acc.y += wv.y*av; acc.z += wv.z*av; acc.w += wv.w*av;
    }
  } else {
    int k0 = kq*16, k1 = k0 + 16;
    for (int k = k0; k < k1; ++k) {
      float av = s_a[684 + k];
      float4 wv = *(const float4*)(ws + OFF_UHZ2T + 2*65536 + k*256 + n);
      acc.x += wv.x*av; acc.y += wv.y*av; acc.z += wv.z*av; acc.w += wv.w*av;
    }
  }
  *(float4*)(&s_p[kq][nq*4]) = acc;
  __syncthreads();
  if (tid < 64) {
    float v = 0.f;
    #pragma unroll
    for (int j = 0; j < 16; ++j) v += s_p[j][tid];
    ws[OFF_G2 + (b*4 + g)*256 + q4*64 + tid] = v;
  }
}

// ---------------- final combine for t=47 ----------------
__global__ void k_final(const float* __restrict__ maskp, const float* __restrict__ bz2,
                        const float* __restrict__ br2, const float* __restrict__ bh2,
                        float* __restrict__ out, float* __restrict__ ws)
{
  int b = blockIdx.x, n = threadIdx.x;
  float h1 = ws[OFF_H1 + b*256 + n];
  float z2 = sigf(ws[OFF_G2 + (b*4 + 0)*256 + n] + bz2[n]);
  float r2 = sigf(ws[OFF_G2 + (b*4 + 1)*256 + n] + br2[n]);
  float h2p = tanhf_(ws[OFF_G2 + (b*4 + 2)*256 + n] + (ws[OFF_G2 + (b*4 + 3)*256 + n] + bh2[n]) * r2);
  float h2 = z2*h1 + (1.f - z2)*h2p;
  float m = maskp[47*16 + b];
  float hv = m*h2 + (1.f - m)*h1;
  out[OUT_H2 + (size_t)(47*16 + b)*256 + n] = hv;
}

extern "C" void kernel_launch(void* const* d_in, const int* in_sizes, int n_in,
                              void* d_out, int out_size, void* d_ws, size_t ws_size,
                              hipStream_t stream)
{
  const float* emb   = (const float*)d_in[0];
  const float* maskp = (const float*)d_in[1];
  const float* ctx   = (const float*)d_in[2];
  const float* cmask = (const float*)d_in[3];
  const float* inits = (const float*)d_in[4];
  const float* Ua    = (const float*)d_in[5];
  const float* Uab   = (const float*)d_in[6];
  const float* Wa    = (const float*)d_in[7];
  const float* Qw    = (const float*)d_in[8];
  const float* Uf    = (const float*)d_in[9];
  const float* Ufb   = (const float*)d_in[10];
  const float* va    = (const float*)d_in[11];
  const float* vab   = (const float*)d_in[12];
  const float* Wyz   = (const float*)d_in[13];
  const float* Wyzb  = (const float*)d_in[14];
  const float* Wyr   = (const float*)d_in[15];
  const float* Wyrb  = (const float*)d_in[16];
  const float* Wyh   = (const float*)d_in[17];
  const float* Wyhb  = (const float*)d_in[18];
  const float* Uhz   = (const float*)d_in[19];
  const float* Uhr   = (const float*)d_in[20];
  const float* Uhh   = (const float*)d_in[21];
  const float* Wcz   = (const float*)d_in[22];
  const float* Wcr   = (const float*)d_in[23];
  const float* Wch   = (const float*)d_in[24];
  const float* Uhz2  = (const float*)d_in[25];
  const float* Uhz2b = (const float*)d_in[26];
  const float* Uhr2  = (const float*)d_in[27];
  const float* Uhr2b = (const float*)d_in[28];
  const float* Uhh2  = (const float*)d_in[29];
  const float* Uhh2b = (const float*)d_in[30];
  float* out = (float*)d_out;
  float* ws  = (float*)d_ws;

  k_prep<<<dim3(6284), dim3(256), 0, stream>>>(Uhz, Uhr, Uhh, Uhz2, Uhr2, Uhh2,
                                               Wyz, Wyr, Wyh, Wa, Wcz, Wcr, Wch, Ua, ws);
  k_kcomb<<<dim3(32), dim3(256), 0, stream>>>(Uf, Qw, ws);
  k_embproj<<<dim3(48), dim3(256), 0, stream>>>(emb, Wyzb, Wyrb, Wyhb, ws);
  k_uactx<<<dim3(768), dim3(512), 0, stream>>>(ctx, ws);

  for (int t = 0; t < 48; ++t) {
    k_gates1<<<dim3(48), dim3(256), 0, stream>>>(t, inits, maskp, Uhz2b, Uhr2b, Uhh2b, out, ws);
    k_h1wah<<<dim3(32), dim3(256), 0, stream>>>(t, maskp, Uab, Ufb, ws);
    k_cover<<<dim3(384), dim3(256), 0, stream>>>(va, ws);
    k_alpha_ct<<<dim3(176), dim3(256), 0, stream>>>(t, ctx, cmask, vab, out, ws);
    k_gates2<<<dim3(256), dim3(256), 0, stream>>>(ws);
  }
  k_final<<<dim3(16), dim3(256), 0, stream>>>(maskp, Uhz2b, Uhr2b, Uhh2b, out, ws);
  (void)in_sizes; (void)n_in; (void)out_size; (void)ws_size;
}